// Round 8
// baseline (118.766 us; speedup 1.0000x reference)
//
#include <hip/hip_runtime.h>
#include <hip/hip_bf16.h>

// LSTM cell fused: C = [x|h] @ [Wx|Wh]^T (gate-per-16col-fragment N layout).
// GEMM M=4096, N=4096, K=2048. 256x256 tile, BK=64, 8 waves (2Mx4N).
// R8 (flatmm): B direct global->register (ping-pong, issued 1 tile early);
// A via LDS (global_load_lds + XOR swizzle, 0 bank conflicts).
// LDS traffic/tile drops 192KB reads + 64KB writes -> 64KB reads + 32KB writes.
// One s_barrier + one vmcnt(0) per K-tile (R7 structure).

constexpr int Mdim = 4096;
constexpr int Ndim = 4096;
constexpr int Kdim = 2048;
constexpr int Hdim = 1024;
constexpr int BM = 256;
constexpr int BN = 256;
constexpr int BK = 64;
constexpr int NT = Kdim / BK;   // 32 K-tiles

using short8 = __attribute__((ext_vector_type(8))) short;
using f32x4  = __attribute__((ext_vector_type(4))) float;

__device__ __forceinline__ float sigmoid_(float x) {
    return 1.f / (1.f + __expf(-x));
}
__device__ __forceinline__ float tanh_(float x) {
    float e = __expf(2.f * x);
    return (e - 1.f) / (e + 1.f);
}

// ---- build A = [x | h] as bf16 [4096][2048] ----
__global__ void build_A(const float* __restrict__ x, const float* __restrict__ h,
                        __hip_bfloat16* __restrict__ A) {
    int idx = blockIdx.x * 256 + threadIdx.x;
    int row = idx >> 8;
    int c8  = (idx & 255) * 8;
    const float* src = (c8 < 1024) ? (x + (size_t)row * 1024 + c8)
                                   : (h + (size_t)row * 1024 + (c8 - 1024));
    float4 f0 = ((const float4*)src)[0];
    float4 f1 = ((const float4*)src)[1];
    union { short8 v; __hip_bfloat16 e[8]; } u;
    u.e[0] = __float2bfloat16(f0.x); u.e[1] = __float2bfloat16(f0.y);
    u.e[2] = __float2bfloat16(f0.z); u.e[3] = __float2bfloat16(f0.w);
    u.e[4] = __float2bfloat16(f1.x); u.e[5] = __float2bfloat16(f1.y);
    u.e[6] = __float2bfloat16(f1.z); u.e[7] = __float2bfloat16(f1.w);
    *(short8*)(A + (size_t)row * Kdim + c8) = u.v;
}

// ---- build B: row n -> gate g=(n>>4)&3, unit j=((n>>6)<<4)|(n&15) ----
__global__ void build_B(const float* __restrict__ Wxi, const float* __restrict__ Whi,
                        const float* __restrict__ Wxf, const float* __restrict__ Whf,
                        const float* __restrict__ Wxg, const float* __restrict__ Whg,
                        const float* __restrict__ Wxo, const float* __restrict__ Who,
                        __hip_bfloat16* __restrict__ B) {
    int idx = blockIdx.x * 256 + threadIdx.x;
    int n  = idx >> 8;
    int c8 = (idx & 255) * 8;
    int g = (n >> 4) & 3;
    int j = ((n >> 6) << 4) | (n & 15);
    const float* Wx = (g == 0) ? Wxi : (g == 1) ? Wxf : (g == 2) ? Wxg : Wxo;
    const float* Wh = (g == 0) ? Whi : (g == 1) ? Whf : (g == 2) ? Whg : Who;
    const float* src = (c8 < 1024) ? (Wx + (size_t)j * 1024 + c8)
                                   : (Wh + (size_t)j * 1024 + (c8 - 1024));
    float4 f0 = ((const float4*)src)[0];
    float4 f1 = ((const float4*)src)[1];
    union { short8 v; __hip_bfloat16 e[8]; } u;
    u.e[0] = __float2bfloat16(f0.x); u.e[1] = __float2bfloat16(f0.y);
    u.e[2] = __float2bfloat16(f0.z); u.e[3] = __float2bfloat16(f0.w);
    u.e[4] = __float2bfloat16(f1.x); u.e[5] = __float2bfloat16(f1.y);
    u.e[6] = __float2bfloat16(f1.z); u.e[7] = __float2bfloat16(f1.w);
    *(short8*)(B + (size_t)n * Kdim + c8) = u.v;
}

#define RD(p) (*(const short8*)(p))

// ---- fused GEMM + LSTM epilogue, flatmm ----
__launch_bounds__(512, 2)
__global__ void lstm_gemm(const __hip_bfloat16* __restrict__ A,
                          const __hip_bfloat16* __restrict__ B,
                          const float* __restrict__ c_prev,
                          const float* __restrict__ b_i, const float* __restrict__ b_f,
                          const float* __restrict__ b_g, const float* __restrict__ b_o,
                          float* __restrict__ out_h, float* __restrict__ out_c) {
    // A only: [dbuf][half][128 rows x 64 cols bf16] = 4 regions x 16 KB = 64 KiB
    __shared__ __hip_bfloat16 lds[2][2][128 * 64];

    const int tid  = threadIdx.x;
    const int lane = tid & 63;
    const int w    = tid >> 6;          // 0..7
    const int wr   = w >> 2;            // 0..1 (M half)
    const int wc   = w & 3;             // 0..3 (N quarter)
    const int l15  = lane & 15, lhi = lane >> 4;

    // XCD-aware swizzle (nwg = 256, divisible by 8)
    int bid = blockIdx.x;
    int swz = (bid & 7) * 32 + (bid >> 3);
    const int bm = (swz >> 4) * BM;
    const int bn = (swz & 15) * BN;

    // A staging: per gll, 512 threads x 16B = 8 KB = 64 rows of 128 B.
    // Source col pre-permuted with the read swizzle: chunk ^= row&7.
    const int srow_  = tid >> 3;                                  // 0..63
    const int schunk = ((tid & 7) ^ ((tid >> 3) & 7)) * 8;        // col element

    // ds_read swizzle: byte-in-row = (kk*64 + lhi*16) ^ ((row&7)<<4), row&7 == l15&7
    const int swz4 = (l15 & 7) << 4;
    const int kof0 = (lhi * 16) ^ swz4;
    const int kof1 = (64 + lhi * 16) ^ swz4;

    // B row base for this lane's 4 fragments: rows bn + wc*64 + b*16 + l15
    const __hip_bfloat16* bRow = B + (size_t)(bn + wc * 64 + l15) * Kdim + lhi * 8;
    // fragment (b, kk) at bRow + b*16*Kdim + kt + kk*32

#define STG1(dstbase, byteoff, grow, kcol)                                      \
    __builtin_amdgcn_global_load_lds(                                           \
        (const __attribute__((address_space(1))) unsigned*)(                    \
            A + (size_t)((grow) + srow_) * Kdim + (kcol) + schunk),             \
        (__attribute__((address_space(3))) unsigned*)(                          \
            (char*)(dstbase) + (byteoff) + tid * 16), 16, 0, 0)

#define STAGE_A(s, kc)                                                          \
    do {                                                                        \
        STG1(&lds[s][0][0], 0,    bm + 0,   kc);                                \
        STG1(&lds[s][0][0], 8192, bm + 64,  kc);                                \
        STG1(&lds[s][1][0], 0,    bm + 128, kc);                                \
        STG1(&lds[s][1][0], 8192, bm + 192, kc);                                \
    } while (0)

#define LOAD_B(dst, kt_)                                                        \
    do {                                                                        \
        _Pragma("unroll")                                                       \
        for (int b_ = 0; b_ < 4; ++b_) {                                        \
            dst[b_][0] = RD(bRow + (size_t)b_ * 16 * Kdim + (kt_));             \
            dst[b_][1] = RD(bRow + (size_t)b_ * 16 * Kdim + (kt_) + 32);        \
        }                                                                       \
    } while (0)

    // one K-tile body: reads A from lds[dcur], stages A(t+1) into lds[dcur^1],
    // loads B(t+1) into BN_, computes with BC.
#define TILE_BODY(t_, dcur, BC, BN_)                                            \
    do {                                                                        \
        const int hasNext = (t_) + 1 < NT;                                      \
        if (hasNext) {                                                          \
            LOAD_B(BN_, ((t_) + 1) * BK);                                       \
            STAGE_A(dcur ^ 1, ((t_) + 1) * BK);                                 \
        }                                                                       \
        const char* Ab = (const char*)&lds[dcur][wr][0] + l15 * 128;            \
        __builtin_amdgcn_s_setprio(1);                                          \
        _Pragma("unroll")                                                       \
        for (int a = 0; a < 8; ++a) {                                           \
            short8 af0 = RD(Ab + a * 2048 + kof0);                              \
            short8 af1 = RD(Ab + a * 2048 + kof1);                              \
            _Pragma("unroll")                                                   \
            for (int b = 0; b < 4; ++b) {                                       \
                acc[a][b] = __builtin_amdgcn_mfma_f32_16x16x32_bf16(            \
                    af0, BC[b][0], acc[a][b], 0, 0, 0);                         \
                acc[a][b] = __builtin_amdgcn_mfma_f32_16x16x32_bf16(            \
                    af1, BC[b][1], acc[a][b], 0, 0, 0);                         \
            }                                                                   \
        }                                                                       \
        __builtin_amdgcn_s_setprio(0);                                          \
        if (hasNext) {                                                          \
            __builtin_amdgcn_sched_barrier(0);                                  \
            asm volatile("s_waitcnt vmcnt(0) lgkmcnt(0)" ::: "memory");         \
            __builtin_amdgcn_s_barrier();                                       \
        }                                                                       \
    } while (0)

    f32x4 acc[8][4];
#pragma unroll
    for (int a = 0; a < 8; ++a)
#pragma unroll
        for (int b = 0; b < 4; ++b)
            acc[a][b] = (f32x4){0.f, 0.f, 0.f, 0.f};

    short8 bfA[4][2], bfB[4][2];

    // ---- prologue: stage A(0), load B(0), drain ----
    STAGE_A(0, 0);
    LOAD_B(bfA, 0);
    __builtin_amdgcn_sched_barrier(0);
    asm volatile("s_waitcnt vmcnt(0)" ::: "memory");
    __builtin_amdgcn_s_barrier();

    for (int tt = 0; tt < NT; tt += 2) {
        TILE_BODY(tt,     0, bfA, bfB);
        TILE_BODY(tt + 1, 1, bfB, bfA);
    }
#undef STG1
#undef STAGE_A
#undef LOAD_B
#undef TILE_BODY

    // ---- fused LSTM epilogue (shuffle-free) ----
    const int j0 = ((bn + wc * 64) >> 6) * 16 + l15;
    const float bi  = b_i[j0];
    const float bf_ = b_f[j0];
    const float bg  = b_g[j0];
    const float bo  = b_o[j0];

#pragma unroll
    for (int a = 0; a < 8; ++a) {
        int mbase = bm + wr * 128 + a * 16 + lhi * 4;
#pragma unroll
        for (int r = 0; r < 4; ++r) {
            int m = mbase + r;
            float vi = acc[a][0][r] + bi;
            float vf = acc[a][1][r] + bf_;
            float vg = acc[a][2][r] + bg;
            float vo = acc[a][3][r] + bo;
            float it = sigmoid_(vi);
            float ft = sigmoid_(vf);
            float gt = tanh_(vg);
            float ot = sigmoid_(vo);
            float cp = c_prev[(size_t)m * Hdim + j0];
            float ct = ft * cp + it * gt;
            float ht = ot * tanh_(ct);
            out_h[(size_t)m * Hdim + j0] = ht;
            out_c[(size_t)m * Hdim + j0] = ct;
        }
    }
}

extern "C" void kernel_launch(void* const* d_in, const int* in_sizes, int n_in,
                              void* d_out, int out_size, void* d_ws, size_t ws_size,
                              hipStream_t stream) {
    const float* x_t    = (const float*)d_in[0];
    const float* h_prev = (const float*)d_in[1];
    const float* c_prev = (const float*)d_in[2];
    const float* W_xi   = (const float*)d_in[3];
    const float* W_hi   = (const float*)d_in[4];
    const float* b_i    = (const float*)d_in[5];
    const float* W_xf   = (const float*)d_in[6];
    const float* W_hf   = (const float*)d_in[7];
    const float* b_f    = (const float*)d_in[8];
    const float* W_xg   = (const float*)d_in[9];
    const float* W_hg   = (const float*)d_in[10];
    const float* b_g    = (const float*)d_in[11];
    const float* W_xo   = (const float*)d_in[12];
    const float* W_ho   = (const float*)d_in[13];
    const float* b_o    = (const float*)d_in[14];

    float* out_h = (float*)d_out;
    float* out_c = out_h + (size_t)Mdim * Hdim;

    __hip_bfloat16* Abf = (__hip_bfloat16*)d_ws;
    __hip_bfloat16* Bbf = Abf + (size_t)Mdim * Kdim;

    build_A<<<4096, 256, 0, stream>>>(x_t, h_prev, Abf);
    build_B<<<4096, 256, 0, stream>>>(W_xi, W_hi, W_xf, W_hf, W_xg, W_hg, W_xo, W_ho, Bbf);

    lstm_gemm<<<dim3((Mdim / BM) * (Ndim / BN)), 512, 0, stream>>>(
        Abf, Bbf, c_prev, b_i, b_f, b_g, b_o, out_h, out_c);
}